// Round 16
// baseline (182.350 us; speedup 1.0000x reference)
//
#include <hip/hip_runtime.h>
#include <math.h>

// LinearAttention: out[n,l,h,m] = (phi(Q[l])·KV[:,m]) / (phi(Q[l])·Ksum + eps)
//   KV[d][m] = sum_s phi(K[s,d]) V[s,m],  Ksum[d] = sum_s phi(K[s,d])
//   phi(x) = elu(x)+1 = x>0 ? x+1 : exp(x)

#define N_B 8
#define S_LEN 8192
#define H_N 8
#define D_DIM 64
#define NH (N_B * H_N)
#define EPS 1e-6f
#define ROWSTRIDE (H_N * D_DIM)   // 512 floats between consecutive s rows
#define NCH 32                     // chunks per (n,h)
#define ROUNDS 2                   // 2 x 128 s-rows per block

typedef __attribute__((ext_vector_type(8)))  __bf16 bf16x8;
typedef __attribute__((ext_vector_type(4)))  float  f32x4;
typedef __attribute__((ext_vector_type(4)))  int    i32x4;

__device__ __forceinline__ float felu1(float x) {
    return x > 0.0f ? x + 1.0f : __expf(x);
}
__device__ __forceinline__ unsigned bfb(float f) {
    __bf16 h = (__bf16)f;                       // RNE convert
    return (unsigned)__builtin_bit_cast(unsigned short, h);
}
__device__ __forceinline__ int pack2bf(float a, float b) {
    return (int)(bfb(a) | (bfb(b) << 16));
}
__device__ __forceinline__ f32x4 ntload4(const float* p) {
    // nt load needs a clang native vector type (ext_vector), not HIP float4
    return __builtin_nontemporal_load((const f32x4*)p);
}

// ---------------- Phase 1a: one-shot MFMA KV partial, NT float4 loads -------
// R14 structure (one-shot rounds, R8 head-innermost remap, XOR-octet d-major
// LDS, verified MFMA frags) + (1) NON-TEMPORAL K/V loads: streaming data, read
// once per launch -- skip L3 insertion (FETCH should rise to ~260 MB; timing
// tells whether L3 half-hits were load-bearing); (2) NCH=32: halves partial
// traffic; (3) launch_bounds(256,5): 5 blocks/CU resident.
__global__ __launch_bounds__(256, 5) void kv_partial_kernel(
        const float* __restrict__ Kin, const float* __restrict__ Vin,
        float* __restrict__ kvp,   // [NH*NCH][64*64]
        float* __restrict__ ksp) { // [NH*NCH][64]
    __shared__ __align__(16) unsigned KT[64 * 64];  // 16 KB: row d, 64 dwords
    __shared__ __align__(16) unsigned VT[64 * 64];  // 16 KB: row m, 64 dwords

    const int b    = blockIdx.x;
    const int h_i  = b & 7;
    const int rest = b >> 3;
    const int c    = rest & (NCH - 1);
    const int n_i  = rest >> 5;                 // NCH = 32
    const int ob   = (n_i * H_N + h_i) * NCH + c;
    const int s0   = c * (ROUNDS * 128);

    const int t = threadIdx.x;
    const int w = t >> 6;        // wave 0..3
    const int l = t & 63;
    const int rq = t >> 4;       // 0..15 row-pair group
    const int cq = t & 15;       // 0..15 col quad (d-cols 4cq..4cq+3)

    const float* Kb = Kin + (size_t)n_i * S_LEN * ROWSTRIDE + (size_t)h_i * D_DIM;
    const float* Vb = Vin + (size_t)n_i * S_LEN * ROWSTRIDE + (size_t)h_i * D_DIM;

    f32x4 kr[8], vr[8];   // [2i+p] = row 2rq+32i+p, cols 4cq..4cq+3
    float ksc[4] = {0.f, 0.f, 0.f, 0.f};

    auto issue = [&](int r) {
        const int sb = s0 + r * 128;
        #pragma unroll
        for (int i = 0; i < 4; ++i)
            #pragma unroll
            for (int p = 0; p < 2; ++p)
                kr[2 * i + p] = ntload4(
                    Kb + (size_t)(sb + 2 * rq + 32 * i + p) * ROWSTRIDE + cq * 4);
        #pragma unroll
        for (int i = 0; i < 4; ++i)
            #pragma unroll
            for (int p = 0; p < 2; ++p)
                vr[2 * i + p] = ntload4(
                    Vb + (size_t)(sb + 2 * rq + 32 * i + p) * ROWSTRIDE + cq * 4);
    };

    // d-major XOR-octet layout (R12/R14 verified scheme):
    // row d = 64 dwords = [sub(0..1)][phys octet po(0..7)][dword rq&3]
    // s-pair jj = rq + 16i (sub = i>>1), logical octet o = 4*(i&1) + (rq>>2),
    // po = o ^ (d&7). Value = pack2bf(s even, s odd).
    auto convwrite = [&]() {
        #pragma unroll
        for (int i = 0; i < 4; ++i) {
            const int sub = i >> 1;
            const int o   = 4 * (i & 1) + (rq >> 2);
            const f32x4 k0 = kr[2 * i], k1 = kr[2 * i + 1];
            const f32x4 v0 = vr[2 * i], v1 = vr[2 * i + 1];
            #pragma unroll
            for (int cc = 0; cc < 4; ++cc) {
                const int d  = 4 * cq + cc;
                const int po = o ^ (d & 7);
                const int dw = d * 64 + sub * 32 + po * 4 + (rq & 3);
                const float f0 = felu1(k0[cc]);
                const float f1 = felu1(k1[cc]);
                ksc[cc] += f0 + f1;
                KT[dw] = (unsigned)pack2bf(f0, f1);
                VT[dw] = (unsigned)pack2bf(v0[cc], v1[cc]);
            }
        }
    };

    f32x4 acc[4];
    #pragma unroll
    for (int i = 0; i < 4; ++i) acc[i] = (f32x4){0.f, 0.f, 0.f, 0.f};

    // compute: wave w owns output d-rows 16w..16w+15 (verified frags)
    const int arow = 16 * w + (l & 15);
    auto compute = [&]() {
        #pragma unroll
        for (int sub = 0; sub < 2; ++sub) {
            #pragma unroll
            for (int ks = 0; ks < 2; ++ks) {
                const int g = ((4 * ks + (l >> 4)) ^ (l & 7)) * 4;
                const bf16x8 A = __builtin_bit_cast(bf16x8,
                    *(const i32x4*)&KT[arow * 64 + sub * 32 + g]);
                #pragma unroll
                for (int mt = 0; mt < 4; ++mt) {
                    const bf16x8 B = __builtin_bit_cast(bf16x8,
                        *(const i32x4*)&VT[(16 * mt + (l & 15)) * 64 + sub * 32 + g]);
                    acc[mt] = __builtin_amdgcn_mfma_f32_16x16x32_bf16(A, B, acc[mt], 0, 0, 0);
                }
            }
        }
    };

    issue(0);
    #pragma unroll
    for (int r = 0; r < ROUNDS; ++r) {
        convwrite();
        __syncthreads();            // LDS visible to all waves
        compute();
        if (r + 1 < ROUNDS) {
            issue(r + 1);           // next burst flies over the barrier
            __syncthreads();        // protect LDS reads before overwrite
        }
    }

    // ---- store partial KV: D col = l&15 (m), row = (l>>4)*4 + reg (d) ----
    float* kvo = kvp + (size_t)ob * (D_DIM * D_DIM);
    #pragma unroll
    for (int mt = 0; mt < 4; ++mt) {
        #pragma unroll
        for (int r = 0; r < 4; ++r) {
            const int row = 16 * w + (l >> 4) * 4 + r;   // d
            const int col = 16 * mt + (l & 15);          // m
            kvo[row * 64 + col] = acc[mt][r];
        }
    }

    // ---- ksum: per-thread col partials (4 cols x 16 rq groups) -> reduce ----
    __syncthreads();                // compute reads done; reuse KT
    float* ksl = (float*)&KT[0];    // [16 rq][64 d]
    *(float4*)&ksl[rq * 64 + 4 * cq] =
        make_float4(ksc[0], ksc[1], ksc[2], ksc[3]);
    __syncthreads();
    if (t < D_DIM) {
        float s = 0.0f;
        #pragma unroll
        for (int g = 0; g < 16; ++g) s += ksl[g * 64 + t];
        ksp[(size_t)ob * D_DIM + t] = s;
    }
}

// ---------------- Phase 1b: reduce partials -> final KV, Ksum ----------------
__global__ __launch_bounds__(256) void kv_reduce_kernel(
        const float* __restrict__ kvp, const float* __restrict__ ksp,
        float* __restrict__ KV, float* __restrict__ Ksum) {
    const int nh = blockIdx.x >> 4;
    const int eb = blockIdx.x & 15;
    const int t  = threadIdx.x;
    const int e  = eb * 256 + t;
    float s = 0.0f;
    const float* base = kvp + (size_t)nh * NCH * (D_DIM * D_DIM) + e;
    #pragma unroll 8
    for (int c = 0; c < NCH; ++c)
        s += base[(size_t)c * (D_DIM * D_DIM)];
    KV[(size_t)nh * (D_DIM * D_DIM) + e] = s;
    if (eb == 0 && t < D_DIM) {
        float ks = 0.0f;
        #pragma unroll 8
        for (int c = 0; c < NCH; ++c)
            ks += ksp[(size_t)nh * NCH * D_DIM + (size_t)c * D_DIM + t];
        Ksum[(size_t)nh * D_DIM + t] = ks;
    }
}

// ---------------- Phase 2: out = (Q·KV) / (Q·Ksum + eps) ----------------
// Grid remap: b = ((n*nblk + rb) * 8) + h (R8, kept -- ~6.4 TB/s measured).
__global__ __launch_bounds__(256) void out_kernel(
        const float* __restrict__ Qin, const float* __restrict__ KV,
        const float* __restrict__ Ksum, float* __restrict__ Out) {
    constexpr int RPB  = 128;
    constexpr int QPAD = 68;
    __shared__ __align__(16) float KVs[D_DIM][D_DIM];   // 16 KB
    __shared__ __align__(16) float Kss[D_DIM];
    __shared__ __align__(16) float Qs[RPB][QPAD];       // 34.8 KB, XOR-swizzled cols

    const int b    = blockIdx.x;
    const int nblk = S_LEN / RPB;          // 64
    const int h_i  = b & 7;
    const int rest = b >> 3;
    const int rb   = rest & (nblk - 1);
    const int n_i  = rest >> 6;            // nblk = 64
    const int nh   = n_i * H_N + h_i;
    const int t    = threadIdx.x;

    const float* Qb = Qin + (size_t)n_i * S_LEN * ROWSTRIDE + (size_t)h_i * D_DIM;
    float*       Ob = Out + (size_t)n_i * S_LEN * ROWSTRIDE + (size_t)h_i * D_DIM;

    {
        const float4* src = (const float4*)(KV + (size_t)nh * (D_DIM * D_DIM));
        float4* dst = (float4*)(&KVs[0][0]);
        #pragma unroll
        for (int i = 0; i < 4; ++i) dst[t + 256 * i] = src[t + 256 * i];
        if (t < 16) ((float4*)Kss)[t] = ((const float4*)(Ksum + (size_t)nh * D_DIM))[t];
    }

    const int ltx = t & 15, lty = t >> 4;
    const int sbase = rb * RPB;
    #pragma unroll
    for (int i = 0; i < 8; ++i) {
        const int row = lty + 16 * i;
        const float4 q = *(const float4*)(Qb + (size_t)(sbase + row) * ROWSTRIDE + ltx * 4);
        float4 f;
        f.x = felu1(q.x); f.y = felu1(q.y); f.z = felu1(q.z); f.w = felu1(q.w);
        const int pc = (ltx * 4) ^ (((row >> 2) & 7) << 2);
        *(float4*)&Qs[row][pc] = f;
    }
    __syncthreads();

    const int rg = t >> 3;                 // 0..31 -> rows rg*4..rg*4+3
    const int mg = t & 7;                  // 0..7  -> cols mg*8..mg*8+7
    const int r0 = rg * 4, m0 = mg * 8;
    const int sw = ((rg & 7) << 2);

    float acc[4][8];
    float zz[4];
    #pragma unroll
    for (int r = 0; r < 4; ++r) {
        zz[r] = 0.0f;
        #pragma unroll
        for (int m = 0; m < 8; ++m) acc[r][m] = 0.0f;
    }

    #pragma unroll
    for (int d0 = 0; d0 < D_DIM; d0 += 4) {
        const float4 ks4 = *(const float4*)&Kss[d0];
        float4 qr[4];
        #pragma unroll
        for (int r = 0; r < 4; ++r) {
            qr[r] = *(const float4*)&Qs[r0 + r][d0 ^ sw];
            zz[r] += qr[r].x * ks4.x + qr[r].y * ks4.y
                   + qr[r].z * ks4.z + qr[r].w * ks4.w;
        }
        #pragma unroll
        for (int j = 0; j < 4; ++j) {
            const float4 kva = *(const float4*)&KVs[d0 + j][m0];
            const float4 kvb = *(const float4*)&KVs[d0 + j][m0 + 4];
            #pragma unroll
            for (int r = 0; r < 4; ++r) {
                const float q = (&qr[r].x)[j];
                acc[r][0] += q * kva.x; acc[r][1] += q * kva.y;
                acc[r][2] += q * kva.z; acc[r][3] += q * kva.w;
                acc[r][4] += q * kvb.x; acc[r][5] += q * kvb.y;
                acc[r][6] += q * kvb.z; acc[r][7] += q * kvb.w;
            }
        }
    }

    #pragma unroll
    for (int r = 0; r < 4; ++r) {
        const float z = 1.0f / (zz[r] + EPS);
        float4 o1, o2;
        o1.x = acc[r][0] * z; o1.y = acc[r][1] * z;
        o1.z = acc[r][2] * z; o1.w = acc[r][3] * z;
        o2.x = acc[r][4] * z; o2.y = acc[r][5] * z;
        o2.z = acc[r][6] * z; o2.w = acc[r][7] * z;
        float* op = Ob + (size_t)(sbase + r0 + r) * ROWSTRIDE + m0;
        *(float4*)op       = o1;
        *(float4*)(op + 4) = o2;
    }
}

extern "C" void kernel_launch(void* const* d_in, const int* in_sizes, int n_in,
                              void* d_out, int out_size, void* d_ws, size_t ws_size,
                              hipStream_t stream) {
    const float* q = (const float*)d_in[0];
    const float* k = (const float*)d_in[1];
    const float* v = (const float*)d_in[2];
    float* out = (float*)d_out;

    float* kvp  = (float*)d_ws;                                   // 33.6 MB
    float* ksp  = kvp + (size_t)NH * NCH * D_DIM * D_DIM;         // 0.5 MB
    float* KVf  = ksp + (size_t)NH * NCH * D_DIM;                 // 1.05 MB
    float* Ksum = KVf + (size_t)NH * D_DIM * D_DIM;

    kv_partial_kernel<<<N_B * NCH * H_N, 256, 0, stream>>>(k, v, kvp, ksp);
    kv_reduce_kernel<<<NH * 16, 256, 0, stream>>>(kvp, ksp, KVf, Ksum);
    out_kernel<<<NH * (S_LEN / 128), 256, 0, stream>>>(q, KVf, Ksum, out);
}

// Round 17
// 160.802 us; speedup vs baseline: 1.1340x; 1.1340x over previous
//
#include <hip/hip_runtime.h>
#include <math.h>

// LinearAttention: out[n,l,h,m] = (phi(Q[l])·KV[:,m]) / (phi(Q[l])·Ksum + eps)
//   KV[d][m] = sum_s phi(K[s,d]) V[s,m],  Ksum[d] = sum_s phi(K[s,d])
//   phi(x) = elu(x)+1 = x>0 ? x+1 : exp(x)

#define N_B 8
#define S_LEN 8192
#define H_N 8
#define D_DIM 64
#define NH (N_B * H_N)
#define EPS 1e-6f
#define ROWSTRIDE (H_N * D_DIM)   // 512 floats between consecutive s rows
#define NCHUNK 16
#define TS 32                      // rows per LDS tile
#define TILES (S_LEN / NCHUNK / TS) // 16 tiles per block

typedef __attribute__((ext_vector_type(8)))  __bf16 bf16x8;
typedef __attribute__((ext_vector_type(4)))  float  f32x4;
typedef __attribute__((ext_vector_type(4)))  int    i32x4;

__device__ __forceinline__ float felu1(float x) {
    return x > 0.0f ? x + 1.0f : __expf(x);
}
__device__ __forceinline__ unsigned bfb(float f) {
    __bf16 h = (__bf16)f;                       // RNE convert
    return (unsigned)__builtin_bit_cast(unsigned short, h);
}
__device__ __forceinline__ int pack2bf(float a, float b) {
    return (int)(bfb(a) | (bfb(b) << 16));
}

// ---------------- Phase 1a: MFMA KV partial (R8 structure, plain bf16) ------
// Best-measured config (R8, 155.4 us total): block = (n, c, h) with head
// innermost in blockIdx (8 consecutive blocks share the same s-rows),
// NCHUNK=16 (minimal 16.6 MB partial traffic), column-gather staging
// (coalesced 256 B/instr, FETCH-clean), T14 split (issue next tile before
// compute, convert+LDS-write after), double-buffered XOR-group LDS
// (0 conflicts). Simplification vs R8: plain RNE bf16, ONE mfma per m-tile
// (hi/lo 3-mfma validated unnecessary at this threshold, R9-R16).
__global__ __launch_bounds__(256) void kv_partial_kernel(
        const float* __restrict__ Kin, const float* __restrict__ Vin,
        float* __restrict__ kvp,   // [NH*NCHUNK][64*64]
        float* __restrict__ ksp) { // [NH*NCHUNK][64]
    __shared__ __align__(16) unsigned KT[2][64 * 32]; // 8 KB per buffer
    __shared__ __align__(16) unsigned VT[2][64 * 32];

    const int b    = blockIdx.x;
    const int h_i  = b & 7;
    const int rest = b >> 3;
    const int c    = rest & (NCHUNK - 1);
    const int n_i  = rest >> 4;                 // NCHUNK = 16
    const int nh   = n_i * H_N + h_i;
    const int ob   = nh * NCHUNK + c;           // logical partial index
    const int s0   = c * (S_LEN / NCHUNK);

    const int t = threadIdx.x;
    const int w = t >> 6;        // wave 0..3
    const int l = t & 63;        // lane
    const int d = l;             // staging column (d for K, m for V)

    const float* Kb = Kin + (size_t)n_i * S_LEN * ROWSTRIDE + (size_t)h_i * D_DIM;
    const float* Vb = Vin + (size_t)n_i * S_LEN * ROWSTRIDE + (size_t)h_i * D_DIM;

    float kraw[8], vraw[8];      // in-flight column gathers (8 s-rows, 1 col)
    float ksum = 0.0f;

    auto issue = [&](int tile) {
        const int sr = s0 + tile * TS + w * 8;
        #pragma unroll
        for (int e = 0; e < 8; ++e) {
            kraw[e] = Kb[(size_t)(sr + e) * ROWSTRIDE + d];
            vraw[e] = Vb[(size_t)(sr + e) * ROWSTRIDE + d];
        }
    };

    // phi (K only), RNE bf16 s-pair pack, XOR-group LDS write.
    // Wave w staged s-octet w -> logical group w, physical = w ^ (d&7).
    auto convert_write = [&](int buf) {
        unsigned kh[4], vh[4];
        #pragma unroll
        for (int p = 0; p < 4; ++p) {
            const float x0 = felu1(kraw[2 * p]);
            const float x1 = felu1(kraw[2 * p + 1]);
            ksum += x0 + x1;
            kh[p] = (unsigned)pack2bf(x0, x1);
            vh[p] = (unsigned)pack2bf(vraw[2 * p], vraw[2 * p + 1]);
        }
        const int ph = (w ^ (d & 7)) * 4;
        unsigned* kr = &KT[buf][d * 32];
        unsigned* vr = &VT[buf][d * 32];
        *(i32x4*)&kr[ph] = (i32x4){(int)kh[0], (int)kh[1], (int)kh[2], (int)kh[3]};
        *(i32x4*)&vr[ph] = (i32x4){(int)vh[0], (int)vh[1], (int)vh[2], (int)vh[3]};
    };

    f32x4 acc[4];
    #pragma unroll
    for (int i = 0; i < 4; ++i) acc[i] = (f32x4){0.f, 0.f, 0.f, 0.f};

    // fragment read offsets (dword units): row*32 + physgroup*4
    const int arow = 16 * w + (l & 15);                 // A row = d (wave slab)
    const int g    = ((l >> 4) ^ (l & 7)) * 4;          // phys group for k-octet
    const int aoff = arow * 32 + g;
    const int brow0 = (l & 15) * 32;                    // B row = m-tile base

    issue(0);
    convert_write(0);
    __syncthreads();

    int cur = 0;
    for (int tile = 0; tile < TILES; ++tile) {
        const bool more = (tile + 1 < TILES);
        if (more) issue(tile + 1);

        const bf16x8 A = __builtin_bit_cast(bf16x8, *(const i32x4*)&KT[cur][aoff]);
        #pragma unroll
        for (int mt = 0; mt < 4; ++mt) {
            const bf16x8 B = __builtin_bit_cast(bf16x8,
                *(const i32x4*)&VT[cur][brow0 + mt * 16 * 32 + g]);
            acc[mt] = __builtin_amdgcn_mfma_f32_16x16x32_bf16(A, B, acc[mt], 0, 0, 0);
        }

        if (more) convert_write(cur ^ 1);   // vmcnt wait lands here (T14)
        __syncthreads();
        cur ^= 1;
    }

    // ---- write partials: D[row][col], col = l&15, row = (l>>4)*4 + reg ----
    float* kvo = kvp + (size_t)ob * (D_DIM * D_DIM);
    #pragma unroll
    for (int mt = 0; mt < 4; ++mt) {
        #pragma unroll
        for (int r = 0; r < 4; ++r) {
            const int row = 16 * w + (l >> 4) * 4 + r;   // d
            const int col = 16 * mt + (l & 15);          // m
            kvo[row * 64 + col] = acc[mt][r];
        }
    }

    // ---- ksum: per-thread column partial -> LDS reduce over 4 waves ----
    float* ksl = (float*)&KT[0][0];
    __syncthreads();
    ksl[w * 64 + d] = ksum;
    __syncthreads();
    if (t < D_DIM) {
        ksp[(size_t)ob * D_DIM + t] =
            ksl[t] + ksl[64 + t] + ksl[128 + t] + ksl[192 + t];
    }
}

// ---------------- Phase 1b: reduce partials -> final KV, Ksum ----------------
__global__ __launch_bounds__(256) void kv_reduce_kernel(
        const float* __restrict__ kvp, const float* __restrict__ ksp,
        float* __restrict__ KV, float* __restrict__ Ksum) {
    const int nh = blockIdx.x >> 4;
    const int eb = blockIdx.x & 15;
    const int t  = threadIdx.x;
    const int e  = eb * 256 + t;
    float s = 0.0f;
    const float* base = kvp + (size_t)nh * NCHUNK * (D_DIM * D_DIM) + e;
    #pragma unroll
    for (int c = 0; c < NCHUNK; ++c)
        s += base[(size_t)c * (D_DIM * D_DIM)];
    KV[(size_t)nh * (D_DIM * D_DIM) + e] = s;
    if (eb == 0 && t < D_DIM) {
        float ks = 0.0f;
        #pragma unroll
        for (int c = 0; c < NCHUNK; ++c)
            ks += ksp[(size_t)nh * NCHUNK * D_DIM + (size_t)c * D_DIM + t];
        Ksum[(size_t)nh * D_DIM + t] = ks;
    }
}

// ---------------- Phase 2: out = (Q·KV) / (Q·Ksum + eps) ----------------
// Grid remap: b = ((n*nblk + rb) * 8) + h (R8, kept -- ~5.7 TB/s timed).
__global__ __launch_bounds__(256) void out_kernel(
        const float* __restrict__ Qin, const float* __restrict__ KV,
        const float* __restrict__ Ksum, float* __restrict__ Out) {
    constexpr int RPB  = 128;
    constexpr int QPAD = 68;
    __shared__ __align__(16) float KVs[D_DIM][D_DIM];   // 16 KB
    __shared__ __align__(16) float Kss[D_DIM];
    __shared__ __align__(16) float Qs[RPB][QPAD];       // 34.8 KB, XOR-swizzled cols

    const int b    = blockIdx.x;
    const int nblk = S_LEN / RPB;          // 64
    const int h_i  = b & 7;
    const int rest = b >> 3;
    const int rb   = rest & (nblk - 1);
    const int n_i  = rest >> 6;            // nblk = 64
    const int nh   = n_i * H_N + h_i;
    const int t    = threadIdx.x;

    const float* Qb = Qin + (size_t)n_i * S_LEN * ROWSTRIDE + (size_t)h_i * D_DIM;
    float*       Ob = Out + (size_t)n_i * S_LEN * ROWSTRIDE + (size_t)h_i * D_DIM;

    {
        const float4* src = (const float4*)(KV + (size_t)nh * (D_DIM * D_DIM));
        float4* dst = (float4*)(&KVs[0][0]);
        #pragma unroll
        for (int i = 0; i < 4; ++i) dst[t + 256 * i] = src[t + 256 * i];
        if (t < 16) ((float4*)Kss)[t] = ((const float4*)(Ksum + (size_t)nh * D_DIM))[t];
    }

    const int ltx = t & 15, lty = t >> 4;
    const int sbase = rb * RPB;
    #pragma unroll
    for (int i = 0; i < 8; ++i) {
        const int row = lty + 16 * i;
        const float4 q = *(const float4*)(Qb + (size_t)(sbase + row) * ROWSTRIDE + ltx * 4);
        float4 f;
        f.x = felu1(q.x); f.y = felu1(q.y); f.z = felu1(q.z); f.w = felu1(q.w);
        const int pc = (ltx * 4) ^ (((row >> 2) & 7) << 2);
        *(float4*)&Qs[row][pc] = f;
    }
    __syncthreads();

    const int rg = t >> 3;                 // 0..31 -> rows rg*4..rg*4+3
    const int mg = t & 7;                  // 0..7  -> cols mg*8..mg*8+7
    const int r0 = rg * 4, m0 = mg * 8;
    const int sw = ((rg & 7) << 2);

    float acc[4][8];
    float zz[4];
    #pragma unroll
    for (int r = 0; r < 4; ++r) {
        zz[r] = 0.0f;
        #pragma unroll
        for (int m = 0; m < 8; ++m) acc[r][m] = 0.0f;
    }

    #pragma unroll
    for (int d0 = 0; d0 < D_DIM; d0 += 4) {
        const float4 ks4 = *(const float4*)&Kss[d0];
        float4 qr[4];
        #pragma unroll
        for (int r = 0; r < 4; ++r) {
            qr[r] = *(const float4*)&Qs[r0 + r][d0 ^ sw];
            zz[r] += qr[r].x * ks4.x + qr[r].y * ks4.y
                   + qr[r].z * ks4.z + qr[r].w * ks4.w;
        }
        #pragma unroll
        for (int j = 0; j < 4; ++j) {
            const float4 kva = *(const float4*)&KVs[d0 + j][m0];
            const float4 kvb = *(const float4*)&KVs[d0 + j][m0 + 4];
            #pragma unroll
            for (int r = 0; r < 4; ++r) {
                const float q = (&qr[r].x)[j];
                acc[r][0] += q * kva.x; acc[r][1] += q * kva.y;
                acc[r][2] += q * kva.z; acc[r][3] += q * kva.w;
                acc[r][4] += q * kvb.x; acc[r][5] += q * kvb.y;
                acc[r][6] += q * kvb.z; acc[r][7] += q * kvb.w;
            }
        }
    }

    #pragma unroll
    for (int r = 0; r < 4; ++r) {
        const float z = 1.0f / (zz[r] + EPS);
        float4 o1, o2;
        o1.x = acc[r][0] * z; o1.y = acc[r][1] * z;
        o1.z = acc[r][2] * z; o1.w = acc[r][3] * z;
        o2.x = acc[r][4] * z; o2.y = acc[r][5] * z;
        o2.z = acc[r][6] * z; o2.w = acc[r][7] * z;
        float* op = Ob + (size_t)(sbase + r0 + r) * ROWSTRIDE + m0;
        *(float4*)op       = o1;
        *(float4*)(op + 4) = o2;
    }
}

extern "C" void kernel_launch(void* const* d_in, const int* in_sizes, int n_in,
                              void* d_out, int out_size, void* d_ws, size_t ws_size,
                              hipStream_t stream) {
    const float* q = (const float*)d_in[0];
    const float* k = (const float*)d_in[1];
    const float* v = (const float*)d_in[2];
    float* out = (float*)d_out;

    float* kvp  = (float*)d_ws;                                   // 16.8 MB
    float* ksp  = kvp + (size_t)NH * NCHUNK * D_DIM * D_DIM;      // 0.26 MB
    float* KVf  = ksp + (size_t)NH * NCHUNK * D_DIM;              // 1.05 MB
    float* Ksum = KVf + (size_t)NH * D_DIM * D_DIM;

    kv_partial_kernel<<<NH * NCHUNK, 256, 0, stream>>>(k, v, kvp, ksp);
    kv_reduce_kernel<<<NH * 16, 256, 0, stream>>>(kvp, ksp, KVf, Ksum);
    out_kernel<<<NH * (S_LEN / 128), 256, 0, stream>>>(q, KVf, Ksum, out);
}